// Round 5
// baseline (300.549 us; speedup 1.0000x reference)
//
#include <hip/hip_runtime.h>
#include <math.h>

#define Bn   128
#define Rn   1152
#define CIn  8
#define Cn   10
#define On   16
#define BO   2048      // Bn*On
#define CBO  20480     // Cn*BO
#define RC   12        // r's per wave
#define PSEG 12        // segq count: each block covers 96 r's (8 waves x 12)
#define GRID 240       // 10c * 2bh * 12segq  (<=256 CUs -> co-residency guaranteed)
#define NTHR 512
#define AGT  __HIP_MEMORY_SCOPE_AGENT

// ---- hand-rolled device-coherent grid barrier (split-K pattern) ------------
__device__ __forceinline__ void gbar(unsigned* bar, int tid)
{
    __syncthreads();   // each wave drains its stores (vmcnt) before arriving
    if (tid == 0) {
        __hip_atomic_fetch_add(bar, 1u, __ATOMIC_RELEASE, AGT);  // wb L2, count
        while (__hip_atomic_load(bar, __ATOMIC_RELAXED, AGT) < (unsigned)GRID)
            __builtin_amdgcn_s_sleep(2);
    }
    __syncthreads();
    __builtin_amdgcn_fence(__ATOMIC_ACQUIRE, "agent");  // invalidate L1/L2
}

// ---------------- pass phase: W tile in LDS, broadcast ds_read --------------
template<int PASS>
__device__ __forceinline__ void pass_phase(
    int blk, int tid,
    const float* __restrict__ XT, const float* __restrict__ W,
    const float* __restrict__ Sprev, float* __restrict__ N2,
    float* __restrict__ PT, float* __restrict__ PL, float* smem)
{
    float (*wlds)[128]   = (float (*)[128])smem;     // [96][128] = 48 KB
    float (*red)[64][34] = (float (*)[64][34])smem;  // [4][64][34] = 34.8 KB

    const int c    = blk / 24;
    const int rem  = blk - c * 24;
    const int bh   = rem / 12;
    const int segq = rem - bh * 12;
    const int w    = tid >> 6;          // 0..7
    const int lane = tid & 63;
    const int b    = bh * 64 + lane;

    // stage W tile: 96 rows * 128 floats = 3072 float4, coalesced
    {
        const float4* gw4 = (const float4*)(W + (size_t)(c * Rn + segq * 96) * 128);
        float4* sw4 = (float4*)smem;
        #pragma unroll
        for (int k = 0; k < 6; ++k)
            sw4[tid + k * 512] = gw4[tid + k * 512];
    }

    // per-thread Vsum (pre-scaled by log2e) from previous passes
    float vs[16];
    if (PASS > 1) {
        float coef[PASS];
        #pragma unroll
        for (int t = 0; t < PASS - 1; ++t) {
            const float n2 = __hip_atomic_load(&N2[t], __ATOMIC_RELAXED, AGT);
            coef[t] = n2 / ((1.0f + n2) * sqrtf(n2)) * 1.4426950408889634f;
        }
        const float* sp = Sprev + c * BO + b * On;
        #pragma unroll
        for (int q = 0; q < 4; ++q) {
            float4 a = make_float4(0.f, 0.f, 0.f, 0.f);
            #pragma unroll
            for (int t = 0; t < PASS - 1; ++t) {
                const float4 s4 = *(const float4*)(sp + t * CBO + q * 4);
                a.x = fmaf(coef[t], s4.x, a.x);
                a.y = fmaf(coef[t], s4.y, a.y);
                a.z = fmaf(coef[t], s4.z, a.z);
                a.w = fmaf(coef[t], s4.w, a.w);
            }
            vs[q * 4 + 0] = a.x; vs[q * 4 + 1] = a.y;
            vs[q * 4 + 2] = a.z; vs[q * 4 + 3] = a.w;
        }
    }

    float tacc[16], lacc[16];
    #pragma unroll
    for (int o = 0; o < 16; ++o) { tacc[o] = 0.0f; lacc[o] = 0.0f; }

    __syncthreads();   // W tile visible

    const float4* XT4 = (const float4*)XT;
    for (int rr = 0; rr < RC; ++rr) {
        const int lrow = w * RC + rr;            // 0..95, wave-uniform
        const int r    = segq * 96 + lrow;
        const float4 xa = XT4[r * 256 + b];
        const float4 xb = XT4[r * 256 + 128 + b];
        const float xi[8] = { xa.x, xa.y, xa.z, xa.w, xb.x, xb.y, xb.z, xb.w };

        float u[16];
        #pragma unroll
        for (int o = 0; o < 16; ++o) u[o] = 0.0f;
        #pragma unroll
        for (int i = 0; i < 8; ++i) {
            const float4 w0 = *(const float4*)&wlds[lrow][i * 16 + 0];
            const float4 w1 = *(const float4*)&wlds[lrow][i * 16 + 4];
            const float4 w2 = *(const float4*)&wlds[lrow][i * 16 + 8];
            const float4 w3 = *(const float4*)&wlds[lrow][i * 16 + 12];
            const float x = xi[i];
            u[0]  = fmaf(x, w0.x, u[0]);  u[1]  = fmaf(x, w0.y, u[1]);
            u[2]  = fmaf(x, w0.z, u[2]);  u[3]  = fmaf(x, w0.w, u[3]);
            u[4]  = fmaf(x, w1.x, u[4]);  u[5]  = fmaf(x, w1.y, u[5]);
            u[6]  = fmaf(x, w1.z, u[6]);  u[7]  = fmaf(x, w1.w, u[7]);
            u[8]  = fmaf(x, w2.x, u[8]);  u[9]  = fmaf(x, w2.y, u[9]);
            u[10] = fmaf(x, w2.z, u[10]); u[11] = fmaf(x, w2.w, u[11]);
            u[12] = fmaf(x, w3.x, u[12]); u[13] = fmaf(x, w3.y, u[13]);
            u[14] = fmaf(x, w3.z, u[14]); u[15] = fmaf(x, w3.w, u[15]);
        }
        #pragma unroll
        for (int o = 0; o < 16; ++o) {
            if (PASS == 1) {
                tacc[o] += u[o];
            } else {
                const float e = exp2f(u[o] * vs[o]);
                lacc[o] += e;
                tacc[o] = fmaf(e, u[o], tacc[o]);
            }
        }
    }

    __syncthreads();   // done reading wlds; smem becomes red

    // two-round cross-wave reduce (keeps LDS at 48 KB)
    if (w < 4) {
        #pragma unroll
        for (int o = 0; o < 16; ++o) {
            red[w][lane][o]      = tacc[o];
            red[w][lane][16 + o] = lacc[o];
        }
    }
    __syncthreads();
    if (w >= 4) {
        #pragma unroll
        for (int o = 0; o < 16; ++o) {
            red[w - 4][lane][o]      += tacc[o];
            red[w - 4][lane][16 + o] += lacc[o];
        }
    }
    __syncthreads();

    {
        const int bl = tid >> 3;          // 0..63
        const int og = tid & 7;           // 0..7 (2 o's each)
        const int bg = bh * 64 + bl;
        float2 tv, lv;
        float* tp = (float*)&tv;
        float* lp = (float*)&lv;
        #pragma unroll
        for (int q = 0; q < 2; ++q) {
            const int o = og * 2 + q;
            tp[q] = red[0][bl][o] + red[1][bl][o] + red[2][bl][o] + red[3][bl][o];
            lp[q] = red[0][bl][16 + o] + red[1][bl][16 + o] +
                    red[2][bl][16 + o] + red[3][bl][16 + o];
        }
        const int idx = segq * CBO + c * BO + bg * On + og * 2;
        *(float2*)(PT + idx) = tv;
        if (PASS > 1) *(float2*)(PL + idx) = lv;
    }
}

// ---------------- combine phase (blocks 0..39) ------------------------------
template<int PASS>
__device__ __forceinline__ void combine_phase(
    int blk, int tid, const float* __restrict__ PT, const float* __restrict__ PL,
    float* __restrict__ Sout, float* __restrict__ n2out, float* smem)
{
    const int i = blk * NTHR + tid;      // 40*512 = 20480
    float T = 0.0f, L = 0.0f;
    #pragma unroll
    for (int s = 0; s < PSEG; ++s) T += PT[s * CBO + i];
    if (PASS == 1) {
        L = (float)Rn;
    } else {
        #pragma unroll
        for (int s = 0; s < PSEG; ++s) L += PL[s * CBO + i];
    }
    const float sv = T / L;
    Sout[i] = sv;
    float sq = sv * sv;
    #pragma unroll
    for (int d = 1; d < 64; d <<= 1) sq += __shfl_xor(sq, d);
    if ((tid & 63) == 0) smem[tid >> 6] = sq;
    __syncthreads();
    if (tid == 0) {
        float s8 = 0.0f;
        #pragma unroll
        for (int k = 0; k < 8; ++k) s8 += smem[k];
        atomicAdd(n2out, s8);
    }
}

// ---------------- fused persistent kernel -----------------------------------
__global__ __launch_bounds__(NTHR, 1)
void fused_kernel(const float* __restrict__ X, const float* __restrict__ W,
                  float* __restrict__ XT, float* __restrict__ PT,
                  float* __restrict__ PL, float* __restrict__ S,
                  float* __restrict__ N2, unsigned* __restrict__ BAR,
                  float* __restrict__ out)
{
    __shared__ __align__(16) float smem[96 * 128];   // 48 KB

    const int blk = blockIdx.x;
    const int tid = threadIdx.x;

    // ---- phase T: transpose x[b][r][i] -> XT[r][g][b][q]
    for (int idx = blk * NTHR + tid; idx < Rn * 256; idx += GRID * NTHR) {
        const int r = idx >> 8;
        const int j = idx & 255;
        const int b = j & 127;
        const int g = j >> 7;
        float4 v = *(const float4*)(X + (size_t)b * (Rn * CIn) + r * CIn + g * 4);
        ((float4*)XT)[r * 256 + g * 128 + b] = v;
    }
    gbar(BAR + 0, tid);

    pass_phase<1>(blk, tid, XT, W, S, N2, PT, PL, smem);
    gbar(BAR + 1, tid);
    if (blk < 40) combine_phase<1>(blk, tid, PT, PL, S + 0 * CBO, N2 + 0, smem);
    gbar(BAR + 2, tid);

    pass_phase<2>(blk, tid, XT, W, S, N2, PT, PL, smem);
    gbar(BAR + 3, tid);
    if (blk < 40) combine_phase<2>(blk, tid, PT, PL, S + 1 * CBO, N2 + 1, smem);
    gbar(BAR + 4, tid);

    pass_phase<3>(blk, tid, XT, W, S, N2, PT, PL, smem);
    gbar(BAR + 5, tid);
    if (blk < 40) combine_phase<3>(blk, tid, PT, PL, S + 2 * CBO, N2 + 2, smem);
    gbar(BAR + 6, tid);

    // ---- final scale
    if (blk < 40) {
        const int i = blk * NTHR + tid;
        const float n2 = __hip_atomic_load(&N2[2], __ATOMIC_RELAXED, AGT);
        const float coef = n2 / ((1.0f + n2) * sqrtf(n2));
        out[i] = coef * S[2 * CBO + i];
    }
}

extern "C" void kernel_launch(void* const* d_in, const int* in_sizes, int n_in,
                              void* d_out, int out_size, void* d_ws, size_t ws_size,
                              hipStream_t stream)
{
    const float* X = (const float*)d_in[0];
    const float* W = (const float*)d_in[1];
    float* ws = (float*)d_ws;
    float* XT  = ws;                         // 1,179,648 floats (4.7 MB)
    float* N2  = XT + Rn * Bn * CIn;         // 4 floats
    unsigned* BAR = (unsigned*)(N2 + 4);     // 8 uints
    float* PT  = N2 + 12;                    // PSEG*CBO = 245,760
    float* PL  = PT + PSEG * CBO;            // PSEG*CBO
    float* S   = PL + PSEG * CBO;            // 3*CBO
    float* out = (float*)d_out;

    hipMemsetAsync(N2, 0, 48, stream);       // zero N2[4] + BAR[8]

    fused_kernel<<<GRID, NTHR, 0, stream>>>(X, W, XT, PT, PL, S, N2, BAR, out);
}

// Round 6
// 161.141 us; speedup vs baseline: 1.8651x; 1.8651x over previous
//
#include <hip/hip_runtime.h>
#include <math.h>

#define Bn   128
#define Rn   1152
#define CIn  8
#define Cn   10
#define On   16
#define BO   2048      // Bn*On
#define CBO  20480     // Cn*BO
#define RC   12        // r's per wave
#define GRID 480       // 10c * 2bh * 24segq
#define LOG2E 1.4426950408889634f
#define INV_R 8.6805555e-4f   // 1/1152

// ws layout: XT[1179648] | TL[102400+16]
// TL: T1 | T2 | L2 | T3 | L3 (20480 each) | ticket (4B, inside the +16 slack)

// ---- transpose x[b][r][i] -> XT[r][g][b][q]  (i = g*4+q) + zero TL/ticket
__global__ __launch_bounds__(256)
void transpose_x(const float* __restrict__ X, float* __restrict__ XT,
                 float* __restrict__ TL)
{
    const int r = blockIdx.x;
    const int b = threadIdx.x & 127;
    const int g = threadIdx.x >> 7;
    float4 v = *(const float4*)(X + (size_t)b * (Rn * CIn) + r * CIn + g * 4);
    ((float4*)XT)[r * 256 + g * 128 + b] = v;
    const int zi = blockIdx.x * 256 + threadIdx.x;     // blocks 0..100 zero TL
    if (zi < 25604) ((float4*)TL)[zi] = make_float4(0.f, 0.f, 0.f, 0.f);
}

// ---- pass kernel: W tile in LDS broadcast; partials merged via atomicAdd;
//      n2 of previous pass computed redundantly in-block (no combine kernel).
template<int PASS>
__global__ __launch_bounds__(256, 2)
void pass_kernel(const float* __restrict__ XT, const float* __restrict__ W,
                 float* __restrict__ TL, float* __restrict__ out)
{
    __shared__ __align__(16) float smem[4 * 64 * 34];   // W[48][128] / red overlay
    __shared__ float sred[8];
    __shared__ int sdone;
    float (*wlds)[128]   = (float (*)[128])smem;
    float (*red)[64][34] = (float (*)[64][34])smem;

    float* T1 = TL;
    float* T2 = TL + CBO;
    float* L2 = TL + 2 * CBO;
    float* T3 = TL + 3 * CBO;
    float* L3 = TL + 4 * CBO;
    unsigned* ticket = (unsigned*)(TL + 5 * CBO);

    const int blk  = blockIdx.x;
    const int c    = blk / 48;
    const int rem  = blk - c * 48;
    const int bh   = rem / 24;
    const int segq = rem - bh * 24;
    const int tid  = threadIdx.x;
    const int w    = tid >> 6;
    const int lane = tid & 63;
    const int b    = bh * 64 + lane;

    // stage W tile: 48 rows * 128 floats, coalesced (overlaps with scans below)
    {
        const float4* gw4 = (const float4*)(W + (size_t)(c * Rn + segq * 48) * 128);
        float4* sw4 = (float4*)smem;
        #pragma unroll
        for (int k = 0; k < 6; ++k)
            sw4[tid + k * 256] = gw4[tid + k * 256];
    }

    // ---- prologue: redundant in-block n2 scan(s) + per-thread vs
    float vs[16];
    if (PASS > 1) {
        float n2a = 0.f, n2b = 0.f;
        const float4* T1v = (const float4*)T1;
        if (PASS == 2) {
            for (int i = tid; i < 5120; i += 256) {
                float4 v = T1v[i];
                v.x *= INV_R; v.y *= INV_R; v.z *= INV_R; v.w *= INV_R;
                n2a += v.x * v.x + v.y * v.y + v.z * v.z + v.w * v.w;
            }
        } else {
            const float4* T2v = (const float4*)T2;
            const float4* L2v = (const float4*)L2;
            for (int i = tid; i < 5120; i += 256) {
                float4 v = T1v[i];
                v.x *= INV_R; v.y *= INV_R; v.z *= INV_R; v.w *= INV_R;
                n2a += v.x * v.x + v.y * v.y + v.z * v.z + v.w * v.w;
                float4 t = T2v[i], l = L2v[i];
                float s0 = t.x / l.x, s1 = t.y / l.y, s2 = t.z / l.z, s3 = t.w / l.w;
                n2b += s0 * s0 + s1 * s1 + s2 * s2 + s3 * s3;
            }
        }
        #pragma unroll
        for (int d = 1; d < 64; d <<= 1) {
            n2a += __shfl_xor(n2a, d);
            n2b += __shfl_xor(n2b, d);
        }
        if (lane == 0) { sred[w] = n2a; sred[4 + w] = n2b; }
        __syncthreads();
        n2a = sred[0] + sred[1] + sred[2] + sred[3];
        n2b = sred[4] + sred[5] + sred[6] + sred[7];

        const float c1 = n2a / ((1.f + n2a) * sqrtf(n2a)) * (LOG2E * INV_R);
        const float* s1p = T1 + c * BO + b * On;
        if (PASS == 2) {
            #pragma unroll
            for (int q = 0; q < 4; ++q) {
                float4 v = *(const float4*)(s1p + q * 4);
                vs[q*4+0] = c1 * v.x; vs[q*4+1] = c1 * v.y;
                vs[q*4+2] = c1 * v.z; vs[q*4+3] = c1 * v.w;
            }
        } else {
            const float c2 = n2b / ((1.f + n2b) * sqrtf(n2b)) * LOG2E;
            const float* t2p = T2 + c * BO + b * On;
            const float* l2p = L2 + c * BO + b * On;
            #pragma unroll
            for (int q = 0; q < 4; ++q) {
                float4 v = *(const float4*)(s1p + q * 4);
                float4 t = *(const float4*)(t2p + q * 4);
                float4 l = *(const float4*)(l2p + q * 4);
                vs[q*4+0] = c1 * v.x + c2 * (t.x / l.x);
                vs[q*4+1] = c1 * v.y + c2 * (t.y / l.y);
                vs[q*4+2] = c1 * v.z + c2 * (t.z / l.z);
                vs[q*4+3] = c1 * v.w + c2 * (t.w / l.w);
            }
        }
    }

    float tacc[16], lacc[16];
    #pragma unroll
    for (int o = 0; o < 16; ++o) { tacc[o] = 0.0f; lacc[o] = 0.0f; }

    __syncthreads();   // W tile visible

    // ---- main loop with explicit next-iteration XT prefetch
    const float4* XT4 = (const float4*)XT;
    const float4* xp  = XT4 + (size_t)(segq * 48 + w * RC) * 256 + b;
    float4 xa = xp[0];
    float4 xb = xp[128];
    for (int rr = 0; rr < RC; ++rr) {
        float4 na = xa, nb = xb;
        if (rr + 1 < RC) {
            na = xp[(rr + 1) * 256];
            nb = xp[(rr + 1) * 256 + 128];
        }
        const int lrow = w * RC + rr;
        const float xi[8] = { xa.x, xa.y, xa.z, xa.w, xb.x, xb.y, xb.z, xb.w };

        float u[16];
        #pragma unroll
        for (int o = 0; o < 16; ++o) u[o] = 0.0f;
        #pragma unroll
        for (int i = 0; i < 8; ++i) {
            const float4 w0 = *(const float4*)&wlds[lrow][i * 16 + 0];
            const float4 w1 = *(const float4*)&wlds[lrow][i * 16 + 4];
            const float4 w2 = *(const float4*)&wlds[lrow][i * 16 + 8];
            const float4 w3 = *(const float4*)&wlds[lrow][i * 16 + 12];
            const float x = xi[i];
            u[0]  = fmaf(x, w0.x, u[0]);  u[1]  = fmaf(x, w0.y, u[1]);
            u[2]  = fmaf(x, w0.z, u[2]);  u[3]  = fmaf(x, w0.w, u[3]);
            u[4]  = fmaf(x, w1.x, u[4]);  u[5]  = fmaf(x, w1.y, u[5]);
            u[6]  = fmaf(x, w1.z, u[6]);  u[7]  = fmaf(x, w1.w, u[7]);
            u[8]  = fmaf(x, w2.x, u[8]);  u[9]  = fmaf(x, w2.y, u[9]);
            u[10] = fmaf(x, w2.z, u[10]); u[11] = fmaf(x, w2.w, u[11]);
            u[12] = fmaf(x, w3.x, u[12]); u[13] = fmaf(x, w3.y, u[13]);
            u[14] = fmaf(x, w3.z, u[14]); u[15] = fmaf(x, w3.w, u[15]);
        }
        #pragma unroll
        for (int o = 0; o < 16; ++o) {
            if (PASS == 1) {
                tacc[o] += u[o];
            } else {
                const float e = exp2f(u[o] * vs[o]);
                lacc[o] += e;
                tacc[o] = fmaf(e, u[o], tacc[o]);
            }
        }
        xa = na; xb = nb;
    }

    __syncthreads();   // done reading wlds; smem becomes red

    #pragma unroll
    for (int o = 0; o < 16; ++o) {
        red[w][lane][o] = tacc[o];
        if (PASS > 1) red[w][lane][16 + o] = lacc[o];
    }
    __syncthreads();

    // ---- block partials -> global accumulators via atomicAdd
    {
        const int bl = tid >> 2;          // 0..63
        const int og = tid & 3;           // 0..3
        const int bg = bh * 64 + bl;
        float* Tslot = (PASS == 1) ? T1 : (PASS == 2) ? T2 : T3;
        float* Lslot = (PASS == 2) ? L2 : L3;
        const int idx = c * BO + bg * On + og * 4;
        #pragma unroll
        for (int q = 0; q < 4; ++q) {
            const int o = og * 4 + q;
            atomicAdd(Tslot + idx + q,
                      red[0][bl][o] + red[1][bl][o] + red[2][bl][o] + red[3][bl][o]);
            if (PASS > 1)
                atomicAdd(Lslot + idx + q,
                          red[0][bl][16+o] + red[1][bl][16+o] +
                          red[2][bl][16+o] + red[3][bl][16+o]);
        }
    }

    // ---- PASS 3: last block computes n2_3 and writes the output
    if (PASS == 3) {
        __syncthreads();
        if (tid == 0) {
            __threadfence();
            sdone = (atomicAdd(ticket, 1u) == GRID - 1);
        }
        __syncthreads();
        if (sdone) {
            __threadfence();
            const float4* T3v = (const float4*)T3;
            const float4* L3v = (const float4*)L3;
            float acc = 0.f;
            for (int i = tid; i < 5120; i += 256) {
                float4 t = T3v[i], l = L3v[i];
                float s0 = t.x / l.x, s1 = t.y / l.y, s2 = t.z / l.z, s3 = t.w / l.w;
                acc += s0 * s0 + s1 * s1 + s2 * s2 + s3 * s3;
            }
            #pragma unroll
            for (int d = 1; d < 64; d <<= 1) acc += __shfl_xor(acc, d);
            if (lane == 0) sred[w] = acc;
            __syncthreads();
            const float n2 = sred[0] + sred[1] + sred[2] + sred[3];
            const float c3 = n2 / ((1.f + n2) * sqrtf(n2));
            for (int i = tid; i < 5120; i += 256) {
                float4 t = T3v[i], l = L3v[i];
                float4 o4;
                o4.x = c3 * t.x / l.x; o4.y = c3 * t.y / l.y;
                o4.z = c3 * t.z / l.z; o4.w = c3 * t.w / l.w;
                ((float4*)out)[i] = o4;
            }
        }
    }
}

extern "C" void kernel_launch(void* const* d_in, const int* in_sizes, int n_in,
                              void* d_out, int out_size, void* d_ws, size_t ws_size,
                              hipStream_t stream)
{
    const float* X = (const float*)d_in[0];
    const float* W = (const float*)d_in[1];
    float* ws = (float*)d_ws;
    float* XT = ws;                          // 1,179,648 floats (4.7 MB)
    float* TL = XT + Rn * Bn * CIn;          // 102,416 floats (slots + ticket)
    float* out = (float*)d_out;

    transpose_x<<<Rn, 256, 0, stream>>>(X, XT, TL);
    pass_kernel<1><<<GRID, 256, 0, stream>>>(XT, W, TL, out);
    pass_kernel<2><<<GRID, 256, 0, stream>>>(XT, W, TL, out);
    pass_kernel<3><<<GRID, 256, 0, stream>>>(XT, W, TL, out);
}

// Round 8
// 152.129 us; speedup vs baseline: 1.9756x; 1.0592x over previous
//
#include <hip/hip_runtime.h>
#include <math.h>

#define Bn   128
#define Rn   1152
#define CIn  8
#define Cn   10
#define On   16
#define BO   2048      // Bn*On
#define CBO  20480     // Cn*BO
#define RC   12        // r's per r-seg wave
#define GRID 480       // 10c * 2bh * 24segq
#define NTHR 512       // 8 waves = 4 r-segs x 2 o-halves
#define LOG2E 1.4426950408889634f
#define INV_R 8.6805555e-4f   // 1/1152

// ws layout: XT[1179648] | TL[102400+16]
// TL: T1 | T2 | L2 | T3 | L3 (20480 each) | ticket (4B)

// ---- transpose x[b][r][i] -> XT[r][g][b][q]  (i = g*4+q) + zero TL/ticket
__global__ __launch_bounds__(256)
void transpose_x(const float* __restrict__ X, float* __restrict__ XT,
                 float* __restrict__ TL)
{
    const int r = blockIdx.x;
    const int b = threadIdx.x & 127;
    const int g = threadIdx.x >> 7;
    float4 v = *(const float4*)(X + (size_t)b * (Rn * CIn) + r * CIn + g * 4);
    ((float4*)XT)[r * 256 + g * 128 + b] = v;
    const int zi = blockIdx.x * 256 + threadIdx.x;
    if (zi < 25604) ((float4*)TL)[zi] = make_float4(0.f, 0.f, 0.f, 0.f);
}

// ---- pass kernel: W tile in LDS broadcast; o split across waves (8 o's/thread);
//      partials merged via atomicAdd; prev-pass n2 scanned redundantly in-block.
template<int PASS>
__global__ __launch_bounds__(NTHR, 4)
void pass_kernel(const float* __restrict__ XT, const float* __restrict__ W,
                 float* __restrict__ TL, float* __restrict__ out)
{
    __shared__ __align__(16) float smem[8 * 64 * 18];   // W[48][128] / red overlay
    __shared__ float sred[16];
    __shared__ int sdone;
    float (*wlds)[128]   = (float (*)[128])smem;        // 24 KB during main loop
    float (*red)[64][18] = (float (*)[64][18])smem;     // 36.9 KB after

    float* T1 = TL;
    float* T2 = TL + CBO;
    float* L2 = TL + 2 * CBO;
    float* T3 = TL + 3 * CBO;
    float* L3 = TL + 4 * CBO;
    unsigned* ticket = (unsigned*)(TL + 5 * CBO);

    const int blk  = blockIdx.x;
    const int c    = blk / 48;
    const int rem  = blk - c * 48;
    const int bh   = rem / 24;
    const int segq = rem - bh * 24;
    const int tid  = threadIdx.x;
    const int w    = tid >> 6;          // 0..7
    const int lane = tid & 63;
    const int b    = bh * 64 + lane;
    const int oh   = w >> 2;            // o-half: 0 -> o0..7, 1 -> o8..15
    const int sw   = w & 3;             // r-seg within block
    const int ohs  = __builtin_amdgcn_readfirstlane(oh * 8);

    // stage W tile: 48 rows * 128 floats = 1536 float4 over 512 threads
    {
        const float4* gw4 = (const float4*)(W + (size_t)(c * Rn + segq * 48) * 128);
        float4* sw4 = (float4*)smem;
        #pragma unroll
        for (int k = 0; k < 3; ++k)
            sw4[tid + k * 512] = gw4[tid + k * 512];
    }

    // ---- prologue: redundant in-block n2 scan(s) + per-thread vs (8 o's)
    float vs[8];
    if (PASS > 1) {
        float n2a = 0.f, n2b = 0.f;
        const float4* T1v = (const float4*)T1;
        if (PASS == 2) {
            for (int i = tid; i < 5120; i += NTHR) {
                float4 v = T1v[i];
                v.x *= INV_R; v.y *= INV_R; v.z *= INV_R; v.w *= INV_R;
                n2a += v.x * v.x + v.y * v.y + v.z * v.z + v.w * v.w;
            }
        } else {
            const float4* T2v = (const float4*)T2;
            const float4* L2v = (const float4*)L2;
            for (int i = tid; i < 5120; i += NTHR) {
                float4 v = T1v[i];
                v.x *= INV_R; v.y *= INV_R; v.z *= INV_R; v.w *= INV_R;
                n2a += v.x * v.x + v.y * v.y + v.z * v.z + v.w * v.w;
                float4 t = T2v[i], l = L2v[i];
                float s0 = t.x / l.x, s1 = t.y / l.y, s2 = t.z / l.z, s3 = t.w / l.w;
                n2b += s0 * s0 + s1 * s1 + s2 * s2 + s3 * s3;
            }
        }
        #pragma unroll
        for (int d = 1; d < 64; d <<= 1) {
            n2a += __shfl_xor(n2a, d);
            n2b += __shfl_xor(n2b, d);
        }
        if (lane == 0) { sred[w] = n2a; sred[8 + w] = n2b; }
        __syncthreads();
        n2a = sred[0] + sred[1] + sred[2] + sred[3] +
              sred[4] + sred[5] + sred[6] + sred[7];
        n2b = sred[8] + sred[9] + sred[10] + sred[11] +
              sred[12] + sred[13] + sred[14] + sred[15];

        const float c1 = n2a / ((1.f + n2a) * sqrtf(n2a)) * (LOG2E * INV_R);
        const float* s1p = T1 + c * BO + b * On + ohs;
        if (PASS == 2) {
            #pragma unroll
            for (int q = 0; q < 2; ++q) {
                float4 v = *(const float4*)(s1p + q * 4);
                vs[q*4+0] = c1 * v.x; vs[q*4+1] = c1 * v.y;
                vs[q*4+2] = c1 * v.z; vs[q*4+3] = c1 * v.w;
            }
        } else {
            const float c2 = n2b / ((1.f + n2b) * sqrtf(n2b)) * LOG2E;
            const float* t2p = T2 + c * BO + b * On + ohs;
            const float* l2p = L2 + c * BO + b * On + ohs;
            #pragma unroll
            for (int q = 0; q < 2; ++q) {
                float4 v = *(const float4*)(s1p + q * 4);
                float4 t = *(const float4*)(t2p + q * 4);
                float4 l = *(const float4*)(l2p + q * 4);
                vs[q*4+0] = c1 * v.x + c2 * (t.x / l.x);
                vs[q*4+1] = c1 * v.y + c2 * (t.y / l.y);
                vs[q*4+2] = c1 * v.z + c2 * (t.z / l.z);
                vs[q*4+3] = c1 * v.w + c2 * (t.w / l.w);
            }
        }
    }

    float tacc[8], lacc[8];
    #pragma unroll
    for (int o = 0; o < 8; ++o) { tacc[o] = 0.0f; lacc[o] = 0.0f; }

    __syncthreads();   // W tile visible

    const float4* XT4 = (const float4*)XT;
    for (int rr = 0; rr < RC; ++rr) {
        const int lrow = sw * RC + rr;            // 0..47, wave-uniform
        const int r    = segq * 48 + lrow;
        const float4 xa = XT4[r * 256 + b];
        const float4 xb = XT4[r * 256 + 128 + b];
        const float xi[8] = { xa.x, xa.y, xa.z, xa.w, xb.x, xb.y, xb.z, xb.w };

        float u[8];
        #pragma unroll
        for (int o = 0; o < 8; ++o) u[o] = 0.0f;
        #pragma unroll
        for (int i = 0; i < 8; ++i) {
            // this wave's 8-float slice of the 16-float o-row: 2x ds_read_b128 bcast
            const float4 w0 = *(const float4*)&wlds[lrow][i * 16 + ohs + 0];
            const float4 w1 = *(const float4*)&wlds[lrow][i * 16 + ohs + 4];
            const float x = xi[i];
            u[0] = fmaf(x, w0.x, u[0]);  u[1] = fmaf(x, w0.y, u[1]);
            u[2] = fmaf(x, w0.z, u[2]);  u[3] = fmaf(x, w0.w, u[3]);
            u[4] = fmaf(x, w1.x, u[4]);  u[5] = fmaf(x, w1.y, u[5]);
            u[6] = fmaf(x, w1.z, u[6]);  u[7] = fmaf(x, w1.w, u[7]);
        }
        #pragma unroll
        for (int o = 0; o < 8; ++o) {
            if (PASS == 1) {
                tacc[o] += u[o];
            } else {
                const float e = exp2f(u[o] * vs[o]);
                lacc[o] += e;
                tacc[o] = fmaf(e, u[o], tacc[o]);
            }
        }
    }

    __syncthreads();   // done reading wlds; smem becomes red

    #pragma unroll
    for (int o = 0; o < 8; ++o) {
        red[w][lane][o] = tacc[o];
        if (PASS > 1) red[w][lane][8 + o] = lacc[o];
    }
    __syncthreads();

    // ---- block partials -> global accumulators via atomicAdd
    {
        const int oh2  = tid >> 8;        // which o-half to reduce
        const int rem2 = tid & 255;
        const int bl   = rem2 >> 2;       // 0..63
        const int oq   = rem2 & 3;        // 2 o's per thread
        const int bg   = bh * 64 + bl;
        float* Tslot = (PASS == 1) ? T1 : (PASS == 2) ? T2 : T3;
        float* Lslot = (PASS == 2) ? L2 : L3;
        const int idx = c * BO + bg * On + oh2 * 8 + oq * 2;
        #pragma unroll
        for (int q = 0; q < 2; ++q) {
            const int o = oq * 2 + q;
            atomicAdd(Tslot + idx + q,
                      red[oh2*4+0][bl][o] + red[oh2*4+1][bl][o] +
                      red[oh2*4+2][bl][o] + red[oh2*4+3][bl][o]);
            if (PASS > 1)
                atomicAdd(Lslot + idx + q,
                          red[oh2*4+0][bl][8+o] + red[oh2*4+1][bl][8+o] +
                          red[oh2*4+2][bl][8+o] + red[oh2*4+3][bl][8+o]);
        }
    }

    // ---- PASS 3: last block computes n2_3 and writes the output
    if (PASS == 3) {
        __syncthreads();
        if (tid == 0) {
            __threadfence();
            sdone = (atomicAdd(ticket, 1u) == GRID - 1);
        }
        __syncthreads();
        if (sdone) {
            __threadfence();
            const float4* T3v = (const float4*)T3;
            const float4* L3v = (const float4*)L3;
            float acc = 0.f;
            for (int i = tid; i < 5120; i += NTHR) {
                float4 t = T3v[i], l = L3v[i];
                float s0 = t.x / l.x, s1 = t.y / l.y, s2 = t.z / l.z, s3 = t.w / l.w;
                acc += s0 * s0 + s1 * s1 + s2 * s2 + s3 * s3;
            }
            #pragma unroll
            for (int d = 1; d < 64; d <<= 1) acc += __shfl_xor(acc, d);
            if (lane == 0) sred[w] = acc;
            __syncthreads();
            float n2 = 0.f;
            #pragma unroll
            for (int k = 0; k < 8; ++k) n2 += sred[k];
            const float c3 = n2 / ((1.f + n2) * sqrtf(n2));
            for (int i = tid; i < 5120; i += NTHR) {
                float4 t = T3v[i], l = L3v[i];
                float4 o4;
                o4.x = c3 * t.x / l.x; o4.y = c3 * t.y / l.y;
                o4.z = c3 * t.z / l.z; o4.w = c3 * t.w / l.w;
                ((float4*)out)[i] = o4;
            }
        }
    }
}

extern "C" void kernel_launch(void* const* d_in, const int* in_sizes, int n_in,
                              void* d_out, int out_size, void* d_ws, size_t ws_size,
                              hipStream_t stream)
{
    const float* X = (const float*)d_in[0];
    const float* W = (const float*)d_in[1];
    float* ws = (float*)d_ws;
    float* XT = ws;                          // 1,179,648 floats (4.7 MB)
    float* TL = XT + Rn * Bn * CIn;          // 102,416 floats (slots + ticket)
    float* out = (float*)d_out;

    transpose_x<<<Rn, 256, 0, stream>>>(X, XT, TL);
    pass_kernel<1><<<GRID, NTHR, 0, stream>>>(XT, W, TL, out);
    pass_kernel<2><<<GRID, NTHR, 0, stream>>>(XT, W, TL, out);
    pass_kernel<3><<<GRID, NTHR, 0, stream>>>(XT, W, TL, out);
}